// Round 11
// baseline (228.207 us; speedup 1.0000x reference)
//
#include <hip/hip_runtime.h>
#include <hip/hip_bf16.h>
#include <stdint.h>

typedef __bf16 bf16x8_t __attribute__((ext_vector_type(8)));
typedef float f32x4 __attribute__((ext_vector_type(4)));
typedef int i32x4 __attribute__((ext_vector_type(4)));

__device__ __forceinline__ unsigned short f2bf_rne(float f) {
  unsigned int u = __float_as_uint(f);
  u += 0x7FFFu + ((u >> 16) & 1u);
  return (unsigned short)(u >> 16);
}

// ---------- kernel 1a (i8): alpha[o] = mean|W[o,:]|, wq[o,:] = sign as i8
__global__ __launch_bounds__(256) void k_prep_w_i8(const float* __restrict__ W,
                                                   signed char* __restrict__ wq,
                                                   float* __restrict__ alpha, int K) {
  const int o = blockIdx.x;
  const float* row = W + (size_t)o * K;
  signed char* orow = wq + (size_t)o * K;
  const int tid = threadIdx.x;
  float s = 0.f;
  const int nj = K / 1024;
  for (int j = 0; j < nj; ++j) {
    int base = j * 1024 + tid * 4;
    float4 v = *reinterpret_cast<const float4*>(row + base);
    s += fabsf(v.x) + fabsf(v.y) + fabsf(v.z) + fabsf(v.w);
    char4 sg;
    sg.x = v.x > 0.f ? 1 : (v.x < 0.f ? -1 : 0);
    sg.y = v.y > 0.f ? 1 : (v.y < 0.f ? -1 : 0);
    sg.z = v.z > 0.f ? 1 : (v.z < 0.f ? -1 : 0);
    sg.w = v.w > 0.f ? 1 : (v.w < 0.f ? -1 : 0);
    *reinterpret_cast<char4*>(orow + base) = sg;
  }
  for (int off = 32; off > 0; off >>= 1) s += __shfl_down(s, off);
  __shared__ float red[4];
  int lane = tid & 63, wid = tid >> 6;
  if (lane == 0) red[wid] = s;
  __syncthreads();
  if (tid == 0) alpha[o] = (red[0] + red[1] + red[2] + red[3]) / (float)K;
}

// ---------- kernel 2a (i8): per-row quantize x -> i8, srow[m] = rowmax/127.
// Row cached in REGISTERS (K<=8192): single global read of x.
__global__ __launch_bounds__(256) void k_quant_x(const float* __restrict__ x,
                                                 signed char* __restrict__ xq,
                                                 float* __restrict__ srw, int K) {
  const int m = blockIdx.x;
  const float* row = x + (size_t)m * K;
  signed char* orow = xq + (size_t)m * K;
  const int tid = threadIdx.x;
  const int nj = K / 1024;
  __shared__ float red[4];
  int lane = tid & 63, wid = tid >> 6;
  float mx = 0.f;
  if (nj <= 8) {
    float4 rv[8];
    for (int j = 0; j < nj; ++j) {
      rv[j] = *reinterpret_cast<const float4*>(row + j * 1024 + tid * 4);
      mx = fmaxf(mx, fmaxf(fmaxf(fabsf(rv[j].x), fabsf(rv[j].y)),
                           fmaxf(fabsf(rv[j].z), fabsf(rv[j].w))));
    }
    for (int off = 32; off > 0; off >>= 1) mx = fmaxf(mx, __shfl_down(mx, off));
    if (lane == 0) red[wid] = mx;
    __syncthreads();
    mx = fmaxf(fmaxf(red[0], red[1]), fmaxf(red[2], red[3]));
    const float inv_s = (mx > 0.f) ? (127.f / mx) : 0.f;
    if (tid == 0) srw[m] = mx * (1.f / 127.f);
    for (int j = 0; j < nj; ++j) {
      char4 q;
      q.x = (signed char)__float2int_rn(rv[j].x * inv_s);
      q.y = (signed char)__float2int_rn(rv[j].y * inv_s);
      q.z = (signed char)__float2int_rn(rv[j].z * inv_s);
      q.w = (signed char)__float2int_rn(rv[j].w * inv_s);
      *reinterpret_cast<char4*>(orow + j * 1024 + tid * 4) = q;
    }
  } else {  // two-pass fallback for very large K
    for (int j = 0; j < nj; ++j) {
      float4 v = *reinterpret_cast<const float4*>(row + j * 1024 + tid * 4);
      mx = fmaxf(mx, fmaxf(fmaxf(fabsf(v.x), fabsf(v.y)), fmaxf(fabsf(v.z), fabsf(v.w))));
    }
    for (int off = 32; off > 0; off >>= 1) mx = fmaxf(mx, __shfl_down(mx, off));
    if (lane == 0) red[wid] = mx;
    __syncthreads();
    mx = fmaxf(fmaxf(red[0], red[1]), fmaxf(red[2], red[3]));
    const float inv_s = (mx > 0.f) ? (127.f / mx) : 0.f;
    if (tid == 0) srw[m] = mx * (1.f / 127.f);
    for (int j = 0; j < nj; ++j) {
      float4 v = *reinterpret_cast<const float4*>(row + j * 1024 + tid * 4);
      char4 q;
      q.x = (signed char)__float2int_rn(v.x * inv_s);
      q.y = (signed char)__float2int_rn(v.y * inv_s);
      q.z = (signed char)__float2int_rn(v.z * inv_s);
      q.w = (signed char)__float2int_rn(v.w * inv_s);
      *reinterpret_cast<char4*>(orow + j * 1024 + tid * 4) = q;
    }
  }
}

// ---------- kernels 1b/2b (bf16 fallback prep, round-0-verified)
__global__ __launch_bounds__(256) void k_prep_w(const float* __restrict__ W,
                                                unsigned short* __restrict__ wb,
                                                float* __restrict__ alpha, int K) {
  const int o = blockIdx.x;
  const float* row = W + (size_t)o * K;
  unsigned short* orow = wb + (size_t)o * K;
  const int tid = threadIdx.x;
  float s = 0.f;
  const int nj = K / 1024;
  for (int j = 0; j < nj; ++j) {
    int base = j * 1024 + tid * 4;
    float4 v = *reinterpret_cast<const float4*>(row + base);
    s += fabsf(v.x) + fabsf(v.y) + fabsf(v.z) + fabsf(v.w);
    ushort4 sg;
    sg.x = v.x > 0.f ? 0x3F80u : (v.x < 0.f ? 0xBF80u : 0u);
    sg.y = v.y > 0.f ? 0x3F80u : (v.y < 0.f ? 0xBF80u : 0u);
    sg.z = v.z > 0.f ? 0x3F80u : (v.z < 0.f ? 0xBF80u : 0u);
    sg.w = v.w > 0.f ? 0x3F80u : (v.w < 0.f ? 0xBF80u : 0u);
    *reinterpret_cast<ushort4*>(orow + base) = sg;
  }
  for (int off = 32; off > 0; off >>= 1) s += __shfl_down(s, off);
  __shared__ float red[4];
  int lane = tid & 63, wid = tid >> 6;
  if (lane == 0) red[wid] = s;
  __syncthreads();
  if (tid == 0) alpha[o] = (red[0] + red[1] + red[2] + red[3]) / (float)K;
}

__global__ __launch_bounds__(256) void k_conv_x(const float* __restrict__ x,
                                                unsigned short* __restrict__ xb,
                                                long long n4) {
  long long i = (long long)blockIdx.x * blockDim.x + threadIdx.x;
  const long long stride = (long long)gridDim.x * blockDim.x;
  for (; i < n4; i += stride) {
    float4 v = reinterpret_cast<const float4*>(x)[i];
    ushort4 o;
    o.x = f2bf_rne(v.x);
    o.y = f2bf_rne(v.y);
    o.z = f2bf_rne(v.z);
    o.w = f2bf_rne(v.w);
    reinterpret_cast<ushort4*>(xb)[i] = o;
  }
}

#define GLDS(gp, lp)                                                                   \
  __builtin_amdgcn_global_load_lds((const __attribute__((address_space(1))) void*)(gp),\
                                   (__attribute__((address_space(3))) void*)(lp), 16, 0, 0)

// ---------- kernel 3i: 256x256 i8 GEMM, BK=64, 4 LDS buffers (32 KiB each),
// 3-tile prefetch, r8-verified handshake (counted vmcnt BEFORE BAR).
// XOR swizzle (r8-verified involution): LDS(row, slot16B) = global(row,
// slot ^ ((row>>1)&3)) -> frag reads hit all 8 bank-groups, 2-way = free.
// C = alpha[col] * srow[row] * (xq . wq^T) + bias[col]
__global__ __launch_bounds__(512, 2) void k_gemm256_i8(
    const signed char* __restrict__ A, const signed char* __restrict__ B,
    const float* __restrict__ alpha, const float* __restrict__ bias,
    const float* __restrict__ srw, float* __restrict__ C,
    int M, int N, int K, int tm, int tn) {
  // buffer b (=T&3) at byte offset b*32768: [A 256x64 | B 256x64] i8
  __shared__ __attribute__((aligned(128))) signed char lds[131072];

  const int nwg = tm * tn;
  const int chunk = nwg >> 3;
  int mT, nT;
  {
    const int bid = blockIdx.x;
    const int mPC = (tn > 0 && chunk % tn == 0) ? (chunk / tn) : 0;
    if ((nwg & 7) == 0 && mPC > 0 && (tm % mPC) == 0) {
      const int c = bid & 7;   // XCD-disjoint A-panels
      const int q = bid >> 3;
      mT = c * mPC + (q % mPC);
      nT = q / mPC;
    } else {
      mT = bid % tm;
      nT = bid / tm;
    }
  }
  const long m0 = (long)mT * 256;
  const int n0 = nT * 256;

  const int tid = threadIdx.x;
  const int lane = tid & 63;
  const int w = tid >> 6;
  const int wr = w >> 2;   // 0..1 -> 128 M-rows
  const int wc = w & 3;    // 0..3 -> 64 N-cols
  const int lr = lane & 15;
  const int l16 = lane >> 4;

  // staging: one wave-GLDS = 64 lanes x 16B = 16 rows x 64B (full K=64 row).
  // lane -> row w*16+(l>>2), LDS slot l&3; source slot pre-swizzled.
  const int sgr = (w << 4) + (lane >> 2);
  const int gsl = (lane & 3) ^ ((lane >> 3) & 3);   // slot ^ ((row>>1)&3)
  const signed char* gA = A + (size_t)(m0 + sgr) * K + gsl * 16;
  const signed char* gB = B + (size_t)(n0 + sgr) * K + gsl * 16;
  const size_t K128 = (size_t)128 * K;
  signed char* const dst0 = lds + (w << 10);  // w*16 rows * 64B, linear

#define STG_TILE(t_, BB)                          \
  do {                                            \
    const signed char* a_ = gA + (t_) * 64;       \
    const signed char* b_ = gB + (t_) * 64;       \
    GLDS(a_, dst0 + (BB));                        \
    GLDS(a_ + K128, dst0 + (BB) + 8192);          \
    GLDS(b_, dst0 + (BB) + 16384);                \
    GLDS(b_ + K128, dst0 + (BB) + 24576);         \
  } while (0)
#define FRAGI(off) (*reinterpret_cast<const i32x4*>(&lds[off]))
#define BAR __builtin_amdgcn_s_barrier()
#define SCHED0 __builtin_amdgcn_sched_barrier(0)

  // frag bases (bytes), swizzled read: frag rows = base + lr with base%8==0,
  // so (row>>1)&3 == (lr>>1)&3 for every fragment.
  const int sx = (lr >> 1) & 3;
  const int pA = (wr * 128 + lr) * 64 + ((l16 ^ sx) << 4);
  const int pB = 16384 + (wc * 64 + lr) * 64 + ((l16 ^ sx) << 4);

  i32x4 acc[8][4];
#pragma unroll
  for (int i = 0; i < 8; ++i)
#pragma unroll
    for (int j = 0; j < 4; ++j) acc[i][j] = (i32x4){0, 0, 0, 0};

  const int NT = K >> 6;  // f256 guarantees NT % 4 == 0, NT >= 4

  auto tile = [&](int T, int BB) {
    SCHED0;  // previous tile's MFMAs stay above
    if (T + 2 < NT) {
      asm volatile("s_waitcnt vmcnt(8)" ::: "memory");   // own tile-T loads done
    } else if (T + 1 < NT) {
      asm volatile("s_waitcnt vmcnt(4)" ::: "memory");
    } else {
      asm volatile("s_waitcnt vmcnt(0)" ::: "memory");
    }
    BAR;     // all waves certified -> tile T fully resident
    SCHED0;  // reads/STG below may not float above the barrier
    i32x4 aF[8], bF[4];
#pragma unroll
    for (int j = 0; j < 4; ++j) bF[j] = FRAGI(BB + pB + j * 1024);
#pragma unroll
    for (int i = 0; i < 8; ++i) aF[i] = FRAGI(BB + pA + i * 1024);
    if (T + 3 < NT) STG_TILE(T + 3, ((T + 3) & 3) * 32768);
#pragma unroll
    for (int i = 0; i < 8; ++i)
#pragma unroll
      for (int j = 0; j < 4; ++j)
        acc[i][j] = __builtin_amdgcn_mfma_i32_16x16x64_i8(aF[i], bF[j], acc[i][j], 0, 0, 0);
  };

  // prologue: stage tiles 0,1,2 (12 GLDS in flight per wave)
  STG_TILE(0, 0);
  STG_TILE(1, 32768);
  STG_TILE(2, 65536);

  for (int T = 0; T < NT; T += 4) {
    tile(T, 0);
    tile(T + 1, 32768);
    tile(T + 2, 65536);
    tile(T + 3, 98304);
  }

  // epilogue: C/D layout col=lane&15, row=(lane>>4)*4+r [m89, dtype-indep m121-128]
  float4 sr[8];
#pragma unroll
  for (int i = 0; i < 8; ++i) {
    const long row = m0 + wr * 128 + i * 16 + l16 * 4;
    sr[i] = *reinterpret_cast<const float4*>(&srw[row]);
  }
#pragma unroll
  for (int j = 0; j < 4; ++j) {
    const int col = n0 + wc * 64 + j * 16 + lr;
    const float al = alpha[col];
    const float bi = bias[col];
#pragma unroll
    for (int i = 0; i < 8; ++i) {
      const long row = m0 + wr * 128 + i * 16 + l16 * 4;
      i32x4 v = acc[i][j];
      C[(size_t)(row + 0) * N + col] = (float)v[0] * sr[i].x * al + bi;
      C[(size_t)(row + 1) * N + col] = (float)v[1] * sr[i].y * al + bi;
      C[(size_t)(row + 2) * N + col] = (float)v[2] * sr[i].z * al + bi;
      C[(size_t)(row + 3) * N + col] = (float)v[3] * sr[i].w * al + bi;
    }
  }
#undef STG_TILE
#undef FRAGI
#undef BAR
#undef SCHED0
}

// ---------- kernel 3a: verified 128x128 bf16 2-phase fallback (round-0, passed)
__global__ __launch_bounds__(256) void k_gemm(
    const unsigned short* __restrict__ A, const unsigned short* __restrict__ B,
    const float* __restrict__ alpha, const float* __restrict__ bias,
    float* __restrict__ C, int M, int N, int K, int tm) {
  __shared__ unsigned short tA[128 * 32];
  __shared__ unsigned short tB[128 * 32];
  const int bid = blockIdx.x;
  const int mT = bid % tm;
  const int nT = bid / tm;
  const int m0 = mT * 128, n0 = nT * 128;
  const int tid = threadIdx.x;
  const int lane = tid & 63;
  const int wid = tid >> 6;
  const int wr = wid >> 1, wc = wid & 1;
  f32x4 acc[4][4];
#pragma unroll
  for (int i = 0; i < 4; ++i)
#pragma unroll
    for (int j = 0; j < 4; ++j) acc[i][j] = (f32x4){0.f, 0.f, 0.f, 0.f};
  const int srow = wid * 16 + (lane >> 2);
  const int scol = (lane & 3) * 8;
  const unsigned short* gA0 = A + (size_t)(m0 + srow) * K + scol;
  const unsigned short* gA1 = A + (size_t)(m0 + 64 + srow) * K + scol;
  const unsigned short* gB0 = B + (size_t)(n0 + srow) * K + scol;
  const unsigned short* gB1 = B + (size_t)(n0 + 64 + srow) * K + scol;
  unsigned short* lA0 = tA + wid * 512;
  unsigned short* lA1 = tA + 2048 + wid * 512;
  unsigned short* lB0 = tB + wid * 512;
  unsigned short* lB1 = tB + 2048 + wid * 512;
  const int lr = lane & 15;
  const int kb = lane >> 4;
  int aoff[4], boff[4];
#pragma unroll
  for (int i = 0; i < 4; ++i) {
    aoff[i] = (wr * 64 + i * 16 + lr) * 32 + kb * 8;
    boff[i] = (wc * 64 + i * 16 + lr) * 32 + kb * 8;
  }
  for (int k0 = 0; k0 < K; k0 += 32) {
    __syncthreads();
    GLDS(gA0 + k0, lA0);
    GLDS(gA1 + k0, lA1);
    GLDS(gB0 + k0, lB0);
    GLDS(gB1 + k0, lB1);
    __syncthreads();
    bf16x8_t af[4], bfr[4];
#pragma unroll
    for (int i = 0; i < 4; ++i) af[i] = *reinterpret_cast<const bf16x8_t*>(&tA[aoff[i]]);
#pragma unroll
    for (int j = 0; j < 4; ++j) bfr[j] = *reinterpret_cast<const bf16x8_t*>(&tB[boff[j]]);
#pragma unroll
    for (int i = 0; i < 4; ++i)
#pragma unroll
      for (int j = 0; j < 4; ++j)
        acc[i][j] = __builtin_amdgcn_mfma_f32_16x16x32_bf16(af[i], bfr[j], acc[i][j], 0, 0, 0);
  }
#pragma unroll
  for (int j = 0; j < 4; ++j) {
    const int col = n0 + wc * 64 + j * 16 + lr;
    const float al = alpha[col];
    const float bi = bias[col];
#pragma unroll
    for (int i = 0; i < 4; ++i) {
      const int row = m0 + wr * 64 + i * 16 + kb * 4;
      f32x4 v = acc[i][j];
#pragma unroll
      for (int r = 0; r < 4; ++r) C[(size_t)(row + r) * N + col] = v[r] * al + bi;
    }
  }
}

// ---------- fallback: slow but correct, zero scratch
__global__ void k_naive(const float* __restrict__ x, const float* __restrict__ W,
                        const float* __restrict__ bias, float* __restrict__ out,
                        int M, int N, int K) {
  int m = blockIdx.x;
  int n = blockIdx.y * 256 + threadIdx.x;
  if (n >= N) return;
  const float* xr = x + (size_t)m * K;
  const float* wr = W + (size_t)n * K;
  float sa = 0.f, s = 0.f;
  for (int i = 0; i < K; ++i) {
    float wv = wr[i];
    sa += fabsf(wv);
    float sg = (wv > 0.f) ? 1.f : ((wv < 0.f) ? -1.f : 0.f);
    s += xr[i] * sg;
  }
  out[(size_t)m * N + n] = (sa / (float)K) * s + bias[n];
}

extern "C" void kernel_launch(void* const* d_in, const int* in_sizes, int n_in,
                              void* d_out, int out_size, void* d_ws, size_t ws_size,
                              hipStream_t stream) {
  const float* x = (const float*)d_in[0];
  const float* w = (const float*)d_in[1];
  const float* bias = (const float*)d_in[2];
  float* out = (float*)d_out;

  const int D_OUT = in_sizes[2];
  const int D_IN = in_sizes[1] / D_OUT;
  const long long M = (long long)in_sizes[0] / D_IN;
  const int N = D_OUT, K = D_IN;

  // i8 workspace layout: xq[M*K] | wq[N*K] | alpha[N] | srow[M]
  const size_t xqB = (size_t)M * K;
  const size_t wqB = (size_t)N * K;
  const size_t need_i8 = xqB + wqB + (size_t)N * 4 + (size_t)M * 4;
  // bf16 fallback layout (round-0): xb[M*K*2] | wb[N*K*2] | alpha[N]
  const size_t xbB = (size_t)M * K * 2;
  const size_t wbB = (size_t)N * K * 2;
  const size_t need_bf = xbB + wbB + (size_t)N * 4;

  const bool kok = (K % 1024 == 0);
  const bool f256 = kok && (ws_size >= need_i8) && (M % 256 == 0) && (N % 256 == 0) &&
                    (K % 256 == 0);
  const bool f128 = kok && (ws_size >= need_bf) && (M % 128 == 0) && (N % 128 == 0) &&
                    (K % 32 == 0);

  if (f256) {
    signed char* xq = (signed char*)d_ws;
    signed char* wq = (signed char*)d_ws + xqB;
    float* alpha = (float*)((char*)d_ws + xqB + wqB);
    float* srow = alpha + N;
    k_prep_w_i8<<<N, 256, 0, stream>>>(w, wq, alpha, K);
    k_quant_x<<<(unsigned)M, 256, 0, stream>>>(x, xq, srow, K);
    const int tm = (int)(M / 256), tn = N / 256;
    k_gemm256_i8<<<tm * tn, 512, 0, stream>>>(xq, wq, alpha, bias, srow, out,
                                              (int)M, N, K, tm, tn);
  } else if (f128) {
    unsigned short* xb = (unsigned short*)d_ws;
    unsigned short* wb = (unsigned short*)((char*)d_ws + xbB);
    float* alpha = (float*)((char*)d_ws + xbB + wbB);
    k_prep_w<<<N, 256, 0, stream>>>(w, wb, alpha, K);
    long long n4 = M * (long long)K / 4;
    k_conv_x<<<2048, 256, 0, stream>>>(x, xb, n4);
    const int tm = (int)(M / 128), tn = N / 128;
    k_gemm<<<tm * tn, 256, 0, stream>>>(xb, wb, alpha, bias, out, (int)M, N, K, tm);
  } else {
    dim3 g((unsigned)M, (unsigned)((N + 255) / 256));
    k_naive<<<g, 256, 0, stream>>>(x, w, bias, out, (int)M, N, K);
  }
}

// Round 12
// 194.477 us; speedup vs baseline: 1.1734x; 1.1734x over previous
//
#include <hip/hip_runtime.h>
#include <hip/hip_bf16.h>
#include <stdint.h>

typedef __bf16 bf16x8_t __attribute__((ext_vector_type(8)));
typedef float f32x4 __attribute__((ext_vector_type(4)));
typedef int i32x4 __attribute__((ext_vector_type(4)));

__device__ __forceinline__ unsigned short f2bf_rne(float f) {
  unsigned int u = __float_as_uint(f);
  u += 0x7FFFu + ((u >> 16) & 1u);
  return (unsigned short)(u >> 16);
}

// ---------- kernel 1a (i8): alpha[o] = mean|W[o,:]|, wq[o,:] = sign as i8
__global__ __launch_bounds__(256) void k_prep_w_i8(const float* __restrict__ W,
                                                   signed char* __restrict__ wq,
                                                   float* __restrict__ alpha, int K) {
  const int o = blockIdx.x;
  const float* row = W + (size_t)o * K;
  signed char* orow = wq + (size_t)o * K;
  const int tid = threadIdx.x;
  float s = 0.f;
  const int nj = K / 1024;
  for (int j = 0; j < nj; ++j) {
    int base = j * 1024 + tid * 4;
    float4 v = *reinterpret_cast<const float4*>(row + base);
    s += fabsf(v.x) + fabsf(v.y) + fabsf(v.z) + fabsf(v.w);
    char4 sg;
    sg.x = v.x > 0.f ? 1 : (v.x < 0.f ? -1 : 0);
    sg.y = v.y > 0.f ? 1 : (v.y < 0.f ? -1 : 0);
    sg.z = v.z > 0.f ? 1 : (v.z < 0.f ? -1 : 0);
    sg.w = v.w > 0.f ? 1 : (v.w < 0.f ? -1 : 0);
    *reinterpret_cast<char4*>(orow + base) = sg;
  }
  for (int off = 32; off > 0; off >>= 1) s += __shfl_down(s, off);
  __shared__ float red[4];
  int lane = tid & 63, wid = tid >> 6;
  if (lane == 0) red[wid] = s;
  __syncthreads();
  if (tid == 0) alpha[o] = (red[0] + red[1] + red[2] + red[3]) / (float)K;
}

// ---------- kernel 2a (i8): per-row quantize x -> i8, srow[m] = rowmax/127.
// K==4096 path holds the row in NAMED registers (rule #20: no runtime-indexed
// arrays) -> single global read. Else two-pass.
__global__ __launch_bounds__(256) void k_quant_x(const float* __restrict__ x,
                                                 signed char* __restrict__ xq,
                                                 float* __restrict__ srw, int K) {
  const int m = blockIdx.x;
  const float* row = x + (size_t)m * K;
  signed char* orow = xq + (size_t)m * K;
  const int tid = threadIdx.x;
  __shared__ float red[4];
  const int lane = tid & 63, wid = tid >> 6;
  float mx = 0.f;
  if (K == 4096) {
    const float4 r0 = *reinterpret_cast<const float4*>(row + 0 * 1024 + tid * 4);
    const float4 r1 = *reinterpret_cast<const float4*>(row + 1 * 1024 + tid * 4);
    const float4 r2 = *reinterpret_cast<const float4*>(row + 2 * 1024 + tid * 4);
    const float4 r3 = *reinterpret_cast<const float4*>(row + 3 * 1024 + tid * 4);
    mx = fmaxf(fmaxf(fmaxf(fabsf(r0.x), fabsf(r0.y)), fmaxf(fabsf(r0.z), fabsf(r0.w))),
               fmaxf(fmaxf(fabsf(r1.x), fabsf(r1.y)), fmaxf(fabsf(r1.z), fabsf(r1.w))));
    mx = fmaxf(mx,
               fmaxf(fmaxf(fmaxf(fabsf(r2.x), fabsf(r2.y)), fmaxf(fabsf(r2.z), fabsf(r2.w))),
                     fmaxf(fmaxf(fabsf(r3.x), fabsf(r3.y)), fmaxf(fabsf(r3.z), fabsf(r3.w)))));
    for (int off = 32; off > 0; off >>= 1) mx = fmaxf(mx, __shfl_down(mx, off));
    if (lane == 0) red[wid] = mx;
    __syncthreads();
    mx = fmaxf(fmaxf(red[0], red[1]), fmaxf(red[2], red[3]));
    const float inv_s = (mx > 0.f) ? (127.f / mx) : 0.f;
    if (tid == 0) srw[m] = mx * (1.f / 127.f);
    char4 q;
    q.x = (signed char)__float2int_rn(r0.x * inv_s);
    q.y = (signed char)__float2int_rn(r0.y * inv_s);
    q.z = (signed char)__float2int_rn(r0.z * inv_s);
    q.w = (signed char)__float2int_rn(r0.w * inv_s);
    *reinterpret_cast<char4*>(orow + 0 * 1024 + tid * 4) = q;
    q.x = (signed char)__float2int_rn(r1.x * inv_s);
    q.y = (signed char)__float2int_rn(r1.y * inv_s);
    q.z = (signed char)__float2int_rn(r1.z * inv_s);
    q.w = (signed char)__float2int_rn(r1.w * inv_s);
    *reinterpret_cast<char4*>(orow + 1 * 1024 + tid * 4) = q;
    q.x = (signed char)__float2int_rn(r2.x * inv_s);
    q.y = (signed char)__float2int_rn(r2.y * inv_s);
    q.z = (signed char)__float2int_rn(r2.z * inv_s);
    q.w = (signed char)__float2int_rn(r2.w * inv_s);
    *reinterpret_cast<char4*>(orow + 2 * 1024 + tid * 4) = q;
    q.x = (signed char)__float2int_rn(r3.x * inv_s);
    q.y = (signed char)__float2int_rn(r3.y * inv_s);
    q.z = (signed char)__float2int_rn(r3.z * inv_s);
    q.w = (signed char)__float2int_rn(r3.w * inv_s);
    *reinterpret_cast<char4*>(orow + 3 * 1024 + tid * 4) = q;
  } else {
    const int nj = K / 1024;
    for (int j = 0; j < nj; ++j) {
      float4 v = *reinterpret_cast<const float4*>(row + j * 1024 + tid * 4);
      mx = fmaxf(mx, fmaxf(fmaxf(fabsf(v.x), fabsf(v.y)), fmaxf(fabsf(v.z), fabsf(v.w))));
    }
    for (int off = 32; off > 0; off >>= 1) mx = fmaxf(mx, __shfl_down(mx, off));
    if (lane == 0) red[wid] = mx;
    __syncthreads();
    mx = fmaxf(fmaxf(red[0], red[1]), fmaxf(red[2], red[3]));
    const float inv_s = (mx > 0.f) ? (127.f / mx) : 0.f;
    if (tid == 0) srw[m] = mx * (1.f / 127.f);
    for (int j = 0; j < nj; ++j) {
      float4 v = *reinterpret_cast<const float4*>(row + j * 1024 + tid * 4);
      char4 q;
      q.x = (signed char)__float2int_rn(v.x * inv_s);
      q.y = (signed char)__float2int_rn(v.y * inv_s);
      q.z = (signed char)__float2int_rn(v.z * inv_s);
      q.w = (signed char)__float2int_rn(v.w * inv_s);
      *reinterpret_cast<char4*>(orow + j * 1024 + tid * 4) = q;
    }
  }
}

#define GLDS(gp, lp)                                                                   \
  __builtin_amdgcn_global_load_lds((const __attribute__((address_space(1))) void*)(gp),\
                                   (__attribute__((address_space(3))) void*)(lp), 16, 0, 0)

// ---------- kernel 3i: 128x256 i8 GEMM, per-wave 64x64, 2-buffer LDS (48 KiB)
// -> 2 blocks/CU: one block's LDS/barrier phase overlaps the other's MFMAs.
// Handshake (r8-verified): counted vmcnt BEFORE BAR1 (publish); lgkmcnt(0)
// before BAR2 (reads complete before buffer overwrite).
// C = alpha[col] * srow[row] * (xq . wq^T) + bias[col]
__global__ __launch_bounds__(512, 4) void k_gemm_i8(
    const signed char* __restrict__ A, const signed char* __restrict__ B,
    const float* __restrict__ alpha, const float* __restrict__ bias,
    const float* __restrict__ srw, float* __restrict__ C,
    int M, int N, int K, int tm, int tn) {
  // buffer b (=T&1) at byte offset b*24576: [A 128x64 | B 256x64] i8
  __shared__ __attribute__((aligned(128))) signed char lds[49152];

  const int nwg = tm * tn;
  const int chunk = nwg >> 3;
  int mT, nT;
  {
    const int bid = blockIdx.x;
    const int mPC = (tn > 0 && chunk % tn == 0) ? (chunk / tn) : 0;
    if ((nwg & 7) == 0 && mPC > 0 && (tm % mPC) == 0) {
      const int c = bid & 7;   // XCD-disjoint A-panels
      const int q = bid >> 3;
      mT = c * mPC + (q % mPC);
      nT = q / mPC;
    } else {
      mT = bid % tm;
      nT = bid / tm;
    }
  }
  const long m0 = (long)mT * 128;
  const int n0 = nT * 256;

  const int tid = threadIdx.x;
  const int lane = tid & 63;
  const int w = tid >> 6;
  const int wr = w >> 2;   // 0..1 -> 64 M-rows each
  const int wc = w & 3;    // 0..3 -> 64 N-cols each
  const int lr = lane & 15;
  const int l16 = lane >> 4;

  // staging: one GLDS = 512 threads x 16B = 128 rows x 64B.
  // thread t -> row w*16+(lane>>2), slot lane&3; source slot pre-swizzled
  // by the verified involution slot ^ ((row>>1)&3) = slot ^ ((lane>>3)&3).
  const int srow = (w << 4) + (lane >> 2);
  const int gsl = (lane & 3) ^ ((lane >> 3) & 3);
  const signed char* gA = A + (size_t)(m0 + srow) * K + gsl * 16;
  const signed char* gB = B + (size_t)(n0 + srow) * K + gsl * 16;
  const size_t K128 = (size_t)128 * K;
  signed char* const dst0 = lds + (w << 10);  // w*16 rows * 64B, linear

#define STG_TILE(t_, BB)                           \
  do {                                             \
    GLDS(gA + (t_) * 64, dst0 + (BB));             \
    GLDS(gB + (t_) * 64, dst0 + (BB) + 8192);      \
    GLDS(gB + (t_) * 64 + K128, dst0 + (BB) + 16384); \
  } while (0)
#define FRAGI(off) (*reinterpret_cast<const i32x4*>(&lds[off]))
#define BAR __builtin_amdgcn_s_barrier()
#define SCHED0 __builtin_amdgcn_sched_barrier(0)

  // frag bases (bytes), swizzled read: frag row bases are %8==0 ->
  // (row>>1)&3 == (lr>>1)&3
  const int sx = (lr >> 1) & 3;
  const int pA = (wr * 64 + lr) * 64 + ((l16 ^ sx) << 4);
  const int pB = 8192 + (wc * 64 + lr) * 64 + ((l16 ^ sx) << 4);

  i32x4 acc[4][4];
#pragma unroll
  for (int i = 0; i < 4; ++i)
#pragma unroll
    for (int j = 0; j < 4; ++j) acc[i][j] = (i32x4){0, 0, 0, 0};

  const int NT = K >> 6;  // f256i guarantees NT even, >= 2

  auto tile = [&](int T, int BB, bool NOT_LAST2, bool NOT_LAST) {
    SCHED0;
    if (NOT_LAST) {
      asm volatile("s_waitcnt vmcnt(3)" ::: "memory");  // own tile-T loads done
    } else {
      asm volatile("s_waitcnt vmcnt(0)" ::: "memory");
    }
    BAR;     // BAR1: all waves certified -> tile T resident
    SCHED0;
    i32x4 aF[4], bF[4];
#pragma unroll
    for (int j = 0; j < 4; ++j) bF[j] = FRAGI(BB + pB + j * 1024);
#pragma unroll
    for (int i = 0; i < 4; ++i) aF[i] = FRAGI(BB + pA + i * 1024);
    asm volatile("s_waitcnt lgkmcnt(0)" ::: "memory");  // my reads complete
    SCHED0;                                             // rule #18 fence
    BAR;     // BAR2: all waves' reads done -> buffer may be overwritten
    if (NOT_LAST2) STG_TILE(T + 2, BB);
#pragma unroll
    for (int i = 0; i < 4; ++i)
#pragma unroll
      for (int j = 0; j < 4; ++j)
        acc[i][j] = __builtin_amdgcn_mfma_i32_16x16x64_i8(aF[i], bF[j], acc[i][j], 0, 0, 0);
  };

  // prologue: stage tiles 0,1 (6 GLDS in flight per wave)
  STG_TILE(0, 0);
  STG_TILE(1, 24576);

  for (int T = 0; T < NT; T += 2) {
    tile(T, 0, T + 2 < NT, true);
    tile(T + 1, 24576, T + 3 < NT, T + 2 < NT);
  }

  // epilogue: C/D layout col=lane&15, row=(lane>>4)*4+r [m89, dtype-indep]
  float4 sr[4];
#pragma unroll
  for (int i = 0; i < 4; ++i) {
    const long row = m0 + wr * 64 + i * 16 + l16 * 4;
    sr[i] = *reinterpret_cast<const float4*>(&srw[row]);
  }
#pragma unroll
  for (int j = 0; j < 4; ++j) {
    const int col = n0 + wc * 64 + j * 16 + lr;
    const float al = alpha[col];
    const float bi = bias[col];
#pragma unroll
    for (int i = 0; i < 4; ++i) {
      const long row = m0 + wr * 64 + i * 16 + l16 * 4;
      i32x4 v = acc[i][j];
      C[(size_t)(row + 0) * N + col] = (float)v[0] * sr[i].x * al + bi;
      C[(size_t)(row + 1) * N + col] = (float)v[1] * sr[i].y * al + bi;
      C[(size_t)(row + 2) * N + col] = (float)v[2] * sr[i].z * al + bi;
      C[(size_t)(row + 3) * N + col] = (float)v[3] * sr[i].w * al + bi;
    }
  }
#undef STG_TILE
#undef FRAGI
#undef BAR
#undef SCHED0
}

// ---------- kernel 3a: verified 128x128 bf16 2-phase fallback (round-0, passed)
__global__ __launch_bounds__(256) void k_gemm(
    const unsigned short* __restrict__ A, const unsigned short* __restrict__ B,
    const float* __restrict__ alpha, const float* __restrict__ bias,
    float* __restrict__ C, int M, int N, int K, int tm) {
  __shared__ unsigned short tA[128 * 32];
  __shared__ unsigned short tB[128 * 32];
  const int bid = blockIdx.x;
  const int mT = bid % tm;
  const int nT = bid / tm;
  const int m0 = mT * 128, n0 = nT * 128;
  const int tid = threadIdx.x;
  const int lane = tid & 63;
  const int wid = tid >> 6;
  const int wr = wid >> 1, wc = wid & 1;
  f32x4 acc[4][4];
#pragma unroll
  for (int i = 0; i < 4; ++i)
#pragma unroll
    for (int j = 0; j < 4; ++j) acc[i][j] = (f32x4){0.f, 0.f, 0.f, 0.f};
  const int srow = wid * 16 + (lane >> 2);
  const int scol = (lane & 3) * 8;
  const unsigned short* gA0 = A + (size_t)(m0 + srow) * K + scol;
  const unsigned short* gA1 = A + (size_t)(m0 + 64 + srow) * K + scol;
  const unsigned short* gB0 = B + (size_t)(n0 + srow) * K + scol;
  const unsigned short* gB1 = B + (size_t)(n0 + 64 + srow) * K + scol;
  unsigned short* lA0 = tA + wid * 512;
  unsigned short* lA1 = tA + 2048 + wid * 512;
  unsigned short* lB0 = tB + wid * 512;
  unsigned short* lB1 = tB + 2048 + wid * 512;
  const int lr = lane & 15;
  const int kb = lane >> 4;
  int aoff[4], boff[4];
#pragma unroll
  for (int i = 0; i < 4; ++i) {
    aoff[i] = (wr * 64 + i * 16 + lr) * 32 + kb * 8;
    boff[i] = (wc * 64 + i * 16 + lr) * 32 + kb * 8;
  }
  for (int k0 = 0; k0 < K; k0 += 32) {
    __syncthreads();
    GLDS(gA0 + k0, lA0);
    GLDS(gA1 + k0, lA1);
    GLDS(gB0 + k0, lB0);
    GLDS(gB1 + k0, lB1);
    __syncthreads();
    bf16x8_t af[4], bfr[4];
#pragma unroll
    for (int i = 0; i < 4; ++i) af[i] = *reinterpret_cast<const bf16x8_t*>(&tA[aoff[i]]);
#pragma unroll
    for (int j = 0; j < 4; ++j) bfr[j] = *reinterpret_cast<const bf16x8_t*>(&tB[boff[j]]);
#pragma unroll
    for (int i = 0; i < 4; ++i)
#pragma unroll
      for (int j = 0; j < 4; ++j)
        acc[i][j] = __builtin_amdgcn_mfma_f32_16x16x32_bf16(af[i], bfr[j], acc[i][j], 0, 0, 0);
  }
#pragma unroll
  for (int j = 0; j < 4; ++j) {
    const int col = n0 + wc * 64 + j * 16 + lr;
    const float al = alpha[col];
    const float bi = bias[col];
#pragma unroll
    for (int i = 0; i < 4; ++i) {
      const int row = m0 + wr * 64 + i * 16 + kb * 4;
      f32x4 v = acc[i][j];
#pragma unroll
      for (int r = 0; r < 4; ++r) C[(size_t)(row + r) * N + col] = v[r] * al + bi;
    }
  }
}

// ---------- bf16 fallback prep (round-0-verified)
__global__ __launch_bounds__(256) void k_prep_w(const float* __restrict__ W,
                                                unsigned short* __restrict__ wb,
                                                float* __restrict__ alpha, int K) {
  const int o = blockIdx.x;
  const float* row = W + (size_t)o * K;
  unsigned short* orow = wb + (size_t)o * K;
  const int tid = threadIdx.x;
  float s = 0.f;
  const int nj = K / 1024;
  for (int j = 0; j < nj; ++j) {
    int base = j * 1024 + tid * 4;
    float4 v = *reinterpret_cast<const float4*>(row + base);
    s += fabsf(v.x) + fabsf(v.y) + fabsf(v.z) + fabsf(v.w);
    ushort4 sg;
    sg.x = v.x > 0.f ? 0x3F80u : (v.x < 0.f ? 0xBF80u : 0u);
    sg.y = v.y > 0.f ? 0x3F80u : (v.y < 0.f ? 0xBF80u : 0u);
    sg.z = v.z > 0.f ? 0x3F80u : (v.z < 0.f ? 0xBF80u : 0u);
    sg.w = v.w > 0.f ? 0x3F80u : (v.w < 0.f ? 0xBF80u : 0u);
    *reinterpret_cast<ushort4*>(orow + base) = sg;
  }
  for (int off = 32; off > 0; off >>= 1) s += __shfl_down(s, off);
  __shared__ float red[4];
  int lane = tid & 63, wid = tid >> 6;
  if (lane == 0) red[wid] = s;
  __syncthreads();
  if (tid == 0) alpha[o] = (red[0] + red[1] + red[2] + red[3]) / (float)K;
}

__global__ __launch_bounds__(256) void k_conv_x(const float* __restrict__ x,
                                                unsigned short* __restrict__ xb,
                                                long long n4) {
  long long i = (long long)blockIdx.x * blockDim.x + threadIdx.x;
  const long long stride = (long long)gridDim.x * blockDim.x;
  for (; i < n4; i += stride) {
    float4 v = reinterpret_cast<const float4*>(x)[i];
    ushort4 o;
    o.x = f2bf_rne(v.x);
    o.y = f2bf_rne(v.y);
    o.z = f2bf_rne(v.z);
    o.w = f2bf_rne(v.w);
    reinterpret_cast<ushort4*>(xb)[i] = o;
  }
}

// ---------- fallback: slow but correct, zero scratch
__global__ void k_naive(const float* __restrict__ x, const float* __restrict__ W,
                        const float* __restrict__ bias, float* __restrict__ out,
                        int M, int N, int K) {
  int m = blockIdx.x;
  int n = blockIdx.y * 256 + threadIdx.x;
  if (n >= N) return;
  const float* xr = x + (size_t)m * K;
  const float* wr = W + (size_t)n * K;
  float sa = 0.f, s = 0.f;
  for (int i = 0; i < K; ++i) {
    float wv = wr[i];
    sa += fabsf(wv);
    float sg = (wv > 0.f) ? 1.f : ((wv < 0.f) ? -1.f : 0.f);
    s += xr[i] * sg;
  }
  out[(size_t)m * N + n] = (sa / (float)K) * s + bias[n];
}

extern "C" void kernel_launch(void* const* d_in, const int* in_sizes, int n_in,
                              void* d_out, int out_size, void* d_ws, size_t ws_size,
                              hipStream_t stream) {
  const float* x = (const float*)d_in[0];
  const float* w = (const float*)d_in[1];
  const float* bias = (const float*)d_in[2];
  float* out = (float*)d_out;

  const int D_OUT = in_sizes[2];
  const int D_IN = in_sizes[1] / D_OUT;
  const long long M = (long long)in_sizes[0] / D_IN;
  const int N = D_OUT, K = D_IN;

  // i8 workspace layout: xq[M*K] | wq[N*K] | alpha[N] | srow[M]
  const size_t xqB = (size_t)M * K;
  const size_t wqB = (size_t)N * K;
  const size_t need_i8 = xqB + wqB + (size_t)N * 4 + (size_t)M * 4;
  // bf16 fallback layout: xb[M*K*2] | wb[N*K*2] | alpha[N]
  const size_t xbB = (size_t)M * K * 2;
  const size_t wbB = (size_t)N * K * 2;
  const size_t need_bf = xbB + wbB + (size_t)N * 4;

  const bool kok = (K % 1024 == 0);
  const bool f256i = kok && (ws_size >= need_i8) && (M % 128 == 0) && (N % 256 == 0) &&
                     (K % 128 == 0);
  const bool f128 = kok && (ws_size >= need_bf) && (M % 128 == 0) && (N % 128 == 0) &&
                    (K % 32 == 0);

  if (f256i) {
    signed char* xq = (signed char*)d_ws;
    signed char* wq = (signed char*)d_ws + xqB;
    float* alpha = (float*)((char*)d_ws + xqB + wqB);
    float* srow = alpha + N;
    k_prep_w_i8<<<N, 256, 0, stream>>>(w, wq, alpha, K);
    k_quant_x<<<(unsigned)M, 256, 0, stream>>>(x, xq, srow, K);
    const int tm = (int)(M / 128), tn = N / 256;
    k_gemm_i8<<<tm * tn, 512, 0, stream>>>(xq, wq, alpha, bias, srow, out,
                                           (int)M, N, K, tm, tn);
  } else if (f128) {
    unsigned short* xb = (unsigned short*)d_ws;
    unsigned short* wb = (unsigned short*)((char*)d_ws + xbB);
    float* alpha = (float*)((char*)d_ws + xbB + wbB);
    k_prep_w<<<N, 256, 0, stream>>>(w, wb, alpha, K);
    long long n4 = M * (long long)K / 4;
    k_conv_x<<<2048, 256, 0, stream>>>(x, xb, n4);
    const int tm = (int)(M / 128), tn = N / 128;
    k_gemm<<<tm * tn, 256, 0, stream>>>(xb, wb, alpha, bias, out, (int)M, N, K, tm);
  } else {
    dim3 g((unsigned)M, (unsigned)((N + 255) / 256));
    k_naive<<<g, 256, 0, stream>>>(x, w, bias, out, (int)M, N, K);
  }
}

// Round 13
// 194.168 us; speedup vs baseline: 1.1753x; 1.0016x over previous
//
#include <hip/hip_runtime.h>
#include <hip/hip_bf16.h>
#include <stdint.h>

typedef __bf16 bf16x8_t __attribute__((ext_vector_type(8)));
typedef float f32x4 __attribute__((ext_vector_type(4)));
typedef int i32x4 __attribute__((ext_vector_type(4)));

__device__ __forceinline__ unsigned short f2bf_rne(float f) {
  unsigned int u = __float_as_uint(f);
  u += 0x7FFFu + ((u >> 16) & 1u);
  return (unsigned short)(u >> 16);
}

// ---------- kernel 1a (i8): alpha[o] = mean|W[o,:]|, wq[o,:] = sign as i8
__global__ __launch_bounds__(256) void k_prep_w_i8(const float* __restrict__ W,
                                                   signed char* __restrict__ wq,
                                                   float* __restrict__ alpha, int K) {
  const int o = blockIdx.x;
  const float* row = W + (size_t)o * K;
  signed char* orow = wq + (size_t)o * K;
  const int tid = threadIdx.x;
  float s = 0.f;
  const int nj = K / 1024;
  for (int j = 0; j < nj; ++j) {
    int base = j * 1024 + tid * 4;
    float4 v = *reinterpret_cast<const float4*>(row + base);
    s += fabsf(v.x) + fabsf(v.y) + fabsf(v.z) + fabsf(v.w);
    char4 sg;
    sg.x = v.x > 0.f ? 1 : (v.x < 0.f ? -1 : 0);
    sg.y = v.y > 0.f ? 1 : (v.y < 0.f ? -1 : 0);
    sg.z = v.z > 0.f ? 1 : (v.z < 0.f ? -1 : 0);
    sg.w = v.w > 0.f ? 1 : (v.w < 0.f ? -1 : 0);
    *reinterpret_cast<char4*>(orow + base) = sg;
  }
  for (int off = 32; off > 0; off >>= 1) s += __shfl_down(s, off);
  __shared__ float red[4];
  int lane = tid & 63, wid = tid >> 6;
  if (lane == 0) red[wid] = s;
  __syncthreads();
  if (tid == 0) alpha[o] = (red[0] + red[1] + red[2] + red[3]) / (float)K;
}

// ---------- kernel 2a (i8): per-row quantize x -> i8, srow[m] = rowmax/127.
// K==4096 path: row in NAMED registers (rule #20) -> single global read.
__global__ __launch_bounds__(256) void k_quant_x(const float* __restrict__ x,
                                                 signed char* __restrict__ xq,
                                                 float* __restrict__ srw, int K) {
  const int m = blockIdx.x;
  const float* row = x + (size_t)m * K;
  signed char* orow = xq + (size_t)m * K;
  const int tid = threadIdx.x;
  __shared__ float red[4];
  const int lane = tid & 63, wid = tid >> 6;
  float mx = 0.f;
  if (K == 4096) {
    const float4 r0 = *reinterpret_cast<const float4*>(row + 0 * 1024 + tid * 4);
    const float4 r1 = *reinterpret_cast<const float4*>(row + 1 * 1024 + tid * 4);
    const float4 r2 = *reinterpret_cast<const float4*>(row + 2 * 1024 + tid * 4);
    const float4 r3 = *reinterpret_cast<const float4*>(row + 3 * 1024 + tid * 4);
    mx = fmaxf(fmaxf(fmaxf(fabsf(r0.x), fabsf(r0.y)), fmaxf(fabsf(r0.z), fabsf(r0.w))),
               fmaxf(fmaxf(fabsf(r1.x), fabsf(r1.y)), fmaxf(fabsf(r1.z), fabsf(r1.w))));
    mx = fmaxf(mx,
               fmaxf(fmaxf(fmaxf(fabsf(r2.x), fabsf(r2.y)), fmaxf(fabsf(r2.z), fabsf(r2.w))),
                     fmaxf(fmaxf(fabsf(r3.x), fabsf(r3.y)), fmaxf(fabsf(r3.z), fabsf(r3.w)))));
    for (int off = 32; off > 0; off >>= 1) mx = fmaxf(mx, __shfl_down(mx, off));
    if (lane == 0) red[wid] = mx;
    __syncthreads();
    mx = fmaxf(fmaxf(red[0], red[1]), fmaxf(red[2], red[3]));
    const float inv_s = (mx > 0.f) ? (127.f / mx) : 0.f;
    if (tid == 0) srw[m] = mx * (1.f / 127.f);
    char4 q;
    q.x = (signed char)__float2int_rn(r0.x * inv_s);
    q.y = (signed char)__float2int_rn(r0.y * inv_s);
    q.z = (signed char)__float2int_rn(r0.z * inv_s);
    q.w = (signed char)__float2int_rn(r0.w * inv_s);
    *reinterpret_cast<char4*>(orow + 0 * 1024 + tid * 4) = q;
    q.x = (signed char)__float2int_rn(r1.x * inv_s);
    q.y = (signed char)__float2int_rn(r1.y * inv_s);
    q.z = (signed char)__float2int_rn(r1.z * inv_s);
    q.w = (signed char)__float2int_rn(r1.w * inv_s);
    *reinterpret_cast<char4*>(orow + 1 * 1024 + tid * 4) = q;
    q.x = (signed char)__float2int_rn(r2.x * inv_s);
    q.y = (signed char)__float2int_rn(r2.y * inv_s);
    q.z = (signed char)__float2int_rn(r2.z * inv_s);
    q.w = (signed char)__float2int_rn(r2.w * inv_s);
    *reinterpret_cast<char4*>(orow + 2 * 1024 + tid * 4) = q;
    q.x = (signed char)__float2int_rn(r3.x * inv_s);
    q.y = (signed char)__float2int_rn(r3.y * inv_s);
    q.z = (signed char)__float2int_rn(r3.z * inv_s);
    q.w = (signed char)__float2int_rn(r3.w * inv_s);
    *reinterpret_cast<char4*>(orow + 3 * 1024 + tid * 4) = q;
  } else {
    const int nj = K / 1024;
    for (int j = 0; j < nj; ++j) {
      float4 v = *reinterpret_cast<const float4*>(row + j * 1024 + tid * 4);
      mx = fmaxf(mx, fmaxf(fmaxf(fabsf(v.x), fabsf(v.y)), fmaxf(fabsf(v.z), fabsf(v.w))));
    }
    for (int off = 32; off > 0; off >>= 1) mx = fmaxf(mx, __shfl_down(mx, off));
    if (lane == 0) red[wid] = mx;
    __syncthreads();
    mx = fmaxf(fmaxf(red[0], red[1]), fmaxf(red[2], red[3]));
    const float inv_s = (mx > 0.f) ? (127.f / mx) : 0.f;
    if (tid == 0) srw[m] = mx * (1.f / 127.f);
    for (int j = 0; j < nj; ++j) {
      float4 v = *reinterpret_cast<const float4*>(row + j * 1024 + tid * 4);
      char4 q;
      q.x = (signed char)__float2int_rn(v.x * inv_s);
      q.y = (signed char)__float2int_rn(v.y * inv_s);
      q.z = (signed char)__float2int_rn(v.z * inv_s);
      q.w = (signed char)__float2int_rn(v.w * inv_s);
      *reinterpret_cast<char4*>(orow + j * 1024 + tid * 4) = q;
    }
  }
}

#define GLDS(gp, lp)                                                                   \
  __builtin_amdgcn_global_load_lds((const __attribute__((address_space(1))) void*)(gp),\
                                   (__attribute__((address_space(3))) void*)(lp), 16, 0, 0)

// ---------- kernel 3i: 128x256 i8 GEMM, per-wave 64x64, THREE rotating LDS
// buffers (72 KiB) -> 2 blocks/CU AND one barrier per K-tile:
// WAR on buffer (T+2)%3 is ordered by BAR(T) (its readers at T-1 drained
// their ds_reads via lgkm waits before reaching the barrier).
// Handshake (r8-verified): counted vmcnt(3) BEFORE BAR (collective publish).
// C = alpha[col] * srow[row] * (xq . wq^T) + bias[col]
__global__ __launch_bounds__(512, 4) void k_gemm_i8(
    const signed char* __restrict__ A, const signed char* __restrict__ B,
    const float* __restrict__ alpha, const float* __restrict__ bias,
    const float* __restrict__ srw, float* __restrict__ C,
    int M, int N, int K, int tm, int tn) {
  // buffer b (=T%3) at byte offset b*24576: [A 128x64 | B 256x64] i8
  __shared__ __attribute__((aligned(128))) signed char lds[73728];

  const int nwg = tm * tn;
  const int chunk = nwg >> 3;
  int mT, nT;
  {
    const int bid = blockIdx.x;
    const int mPC = (tn > 0 && chunk % tn == 0) ? (chunk / tn) : 0;
    if ((nwg & 7) == 0 && mPC > 0 && (tm % mPC) == 0) {
      const int c = bid & 7;   // XCD-disjoint A-panels
      const int q = bid >> 3;
      mT = c * mPC + (q % mPC);
      nT = q / mPC;
    } else {
      mT = bid % tm;
      nT = bid / tm;
    }
  }
  const long m0 = (long)mT * 128;
  const int n0 = nT * 256;

  const int tid = threadIdx.x;
  const int lane = tid & 63;
  const int w = tid >> 6;
  const int wr = w >> 2;   // 0..1 -> 64 M-rows each
  const int wc = w & 3;    // 0..3 -> 64 N-cols each
  const int lr = lane & 15;
  const int l16 = lane >> 4;

  // staging: one GLDS = 512 threads x 16B = 128 rows x 64B.
  // thread -> row w*16+(lane>>2), slot lane&3; source slot pre-swizzled by the
  // verified involution slot ^ ((row>>1)&3) = slot ^ ((lane>>3)&3).
  const int srow = (w << 4) + (lane >> 2);
  const int gsl = (lane & 3) ^ ((lane >> 3) & 3);
  const signed char* gA = A + (size_t)(m0 + srow) * K + gsl * 16;
  const signed char* gB = B + (size_t)(n0 + srow) * K + gsl * 16;
  const size_t K128 = (size_t)128 * K;
  signed char* const dst0 = lds + (w << 10);  // w*16 rows * 64B, linear

#define STG_TILE(t_, BB)                              \
  do {                                                \
    GLDS(gA + (t_) * 64, dst0 + (BB));                \
    GLDS(gB + (t_) * 64, dst0 + (BB) + 8192);         \
    GLDS(gB + (t_) * 64 + K128, dst0 + (BB) + 16384); \
  } while (0)
#define FRAGI(off) (*reinterpret_cast<const i32x4*>(&lds[off]))
#define BAR __builtin_amdgcn_s_barrier()
#define SCHED0 __builtin_amdgcn_sched_barrier(0)

  // frag bases (bytes), swizzled read: frag row bases %8==0 ->
  // (row>>1)&3 == (lr>>1)&3
  const int sx = (lr >> 1) & 3;
  const int pA = (wr * 64 + lr) * 64 + ((l16 ^ sx) << 4);
  const int pB = 8192 + (wc * 64 + lr) * 64 + ((l16 ^ sx) << 4);

  i32x4 acc[4][4];
#pragma unroll
  for (int i = 0; i < 4; ++i)
#pragma unroll
    for (int j = 0; j < 4; ++j) acc[i][j] = (i32x4){0, 0, 0, 0};

  const int NT = K >> 6;  // f256i guarantees NT >= 2

  // prologue: stage tiles 0,1 (6 GLDS in flight per block)
  STG_TILE(0, 0);
  STG_TILE(1, 24576);

  int rb = 0;        // read buffer (tile T)
  int sb = 49152;    // stage buffer (tile T+2)
  for (int T = 0; T < NT; ++T) {
    SCHED0;  // previous tile's MFMAs stay above
    if (T + 1 < NT) {
      asm volatile("s_waitcnt vmcnt(3)" ::: "memory");  // own tile-T loads done
    } else {
      asm volatile("s_waitcnt vmcnt(0)" ::: "memory");
    }
    BAR;     // all waves certified -> tile T resident; also orders buffer reuse
    SCHED0;  // reads/STG below may not float above the barrier
    i32x4 aF[4], bF[4];
#pragma unroll
    for (int j = 0; j < 4; ++j) bF[j] = FRAGI(rb + pB + j * 1024);
#pragma unroll
    for (int i = 0; i < 4; ++i) aF[i] = FRAGI(rb + pA + i * 1024);
    if (T + 2 < NT) STG_TILE(T + 2, sb);
    __builtin_amdgcn_s_setprio(1);
#pragma unroll
    for (int i = 0; i < 4; ++i)
#pragma unroll
      for (int j = 0; j < 4; ++j)
        acc[i][j] = __builtin_amdgcn_mfma_i32_16x16x64_i8(aF[i], bF[j], acc[i][j], 0, 0, 0);
    __builtin_amdgcn_s_setprio(0);
    rb += 24576; if (rb == 73728) rb = 0;
    sb += 24576; if (sb == 73728) sb = 0;
  }

  // epilogue: C/D layout col=lane&15, row=(lane>>4)*4+r [m89, dtype-indep]
  float4 sr[4];
#pragma unroll
  for (int i = 0; i < 4; ++i) {
    const long row = m0 + wr * 64 + i * 16 + l16 * 4;
    sr[i] = *reinterpret_cast<const float4*>(&srw[row]);
  }
#pragma unroll
  for (int j = 0; j < 4; ++j) {
    const int col = n0 + wc * 64 + j * 16 + lr;
    const float al = alpha[col];
    const float bi = bias[col];
#pragma unroll
    for (int i = 0; i < 4; ++i) {
      const long row = m0 + wr * 64 + i * 16 + l16 * 4;
      i32x4 v = acc[i][j];
      C[(size_t)(row + 0) * N + col] = (float)v[0] * sr[i].x * al + bi;
      C[(size_t)(row + 1) * N + col] = (float)v[1] * sr[i].y * al + bi;
      C[(size_t)(row + 2) * N + col] = (float)v[2] * sr[i].z * al + bi;
      C[(size_t)(row + 3) * N + col] = (float)v[3] * sr[i].w * al + bi;
    }
  }
#undef STG_TILE
#undef FRAGI
#undef BAR
#undef SCHED0
}

// ---------- kernel 3a: verified 128x128 bf16 2-phase fallback (round-0, passed)
__global__ __launch_bounds__(256) void k_gemm(
    const unsigned short* __restrict__ A, const unsigned short* __restrict__ B,
    const float* __restrict__ alpha, const float* __restrict__ bias,
    float* __restrict__ C, int M, int N, int K, int tm) {
  __shared__ unsigned short tA[128 * 32];
  __shared__ unsigned short tB[128 * 32];
  const int bid = blockIdx.x;
  const int mT = bid % tm;
  const int nT = bid / tm;
  const int m0 = mT * 128, n0 = nT * 128;
  const int tid = threadIdx.x;
  const int lane = tid & 63;
  const int wid = tid >> 6;
  const int wr = wid >> 1, wc = wid & 1;
  f32x4 acc[4][4];
#pragma unroll
  for (int i = 0; i < 4; ++i)
#pragma unroll
    for (int j = 0; j < 4; ++j) acc[i][j] = (f32x4){0.f, 0.f, 0.f, 0.f};
  const int srow = wid * 16 + (lane >> 2);
  const int scol = (lane & 3) * 8;
  const unsigned short* gA0 = A + (size_t)(m0 + srow) * K + scol;
  const unsigned short* gA1 = A + (size_t)(m0 + 64 + srow) * K + scol;
  const unsigned short* gB0 = B + (size_t)(n0 + srow) * K + scol;
  const unsigned short* gB1 = B + (size_t)(n0 + 64 + srow) * K + scol;
  unsigned short* lA0 = tA + wid * 512;
  unsigned short* lA1 = tA + 2048 + wid * 512;
  unsigned short* lB0 = tB + wid * 512;
  unsigned short* lB1 = tB + 2048 + wid * 512;
  const int lr = lane & 15;
  const int kb = lane >> 4;
  int aoff[4], boff[4];
#pragma unroll
  for (int i = 0; i < 4; ++i) {
    aoff[i] = (wr * 64 + i * 16 + lr) * 32 + kb * 8;
    boff[i] = (wc * 64 + i * 16 + lr) * 32 + kb * 8;
  }
  for (int k0 = 0; k0 < K; k0 += 32) {
    __syncthreads();
    GLDS(gA0 + k0, lA0);
    GLDS(gA1 + k0, lA1);
    GLDS(gB0 + k0, lB0);
    GLDS(gB1 + k0, lB1);
    __syncthreads();
    bf16x8_t af[4], bfr[4];
#pragma unroll
    for (int i = 0; i < 4; ++i) af[i] = *reinterpret_cast<const bf16x8_t*>(&tA[aoff[i]]);
#pragma unroll
    for (int j = 0; j < 4; ++j) bfr[j] = *reinterpret_cast<const bf16x8_t*>(&tB[boff[j]]);
#pragma unroll
    for (int i = 0; i < 4; ++i)
#pragma unroll
      for (int j = 0; j < 4; ++j)
        acc[i][j] = __builtin_amdgcn_mfma_f32_16x16x32_bf16(af[i], bfr[j], acc[i][j], 0, 0, 0);
  }
#pragma unroll
  for (int j = 0; j < 4; ++j) {
    const int col = n0 + wc * 64 + j * 16 + lr;
    const float al = alpha[col];
    const float bi = bias[col];
#pragma unroll
    for (int i = 0; i < 4; ++i) {
      const int row = m0 + wr * 64 + i * 16 + kb * 4;
      f32x4 v = acc[i][j];
#pragma unroll
      for (int r = 0; r < 4; ++r) C[(size_t)(row + r) * N + col] = v[r] * al + bi;
    }
  }
}

// ---------- bf16 fallback prep (round-0-verified)
__global__ __launch_bounds__(256) void k_prep_w(const float* __restrict__ W,
                                                unsigned short* __restrict__ wb,
                                                float* __restrict__ alpha, int K) {
  const int o = blockIdx.x;
  const float* row = W + (size_t)o * K;
  unsigned short* orow = wb + (size_t)o * K;
  const int tid = threadIdx.x;
  float s = 0.f;
  const int nj = K / 1024;
  for (int j = 0; j < nj; ++j) {
    int base = j * 1024 + tid * 4;
    float4 v = *reinterpret_cast<const float4*>(row + base);
    s += fabsf(v.x) + fabsf(v.y) + fabsf(v.z) + fabsf(v.w);
    ushort4 sg;
    sg.x = v.x > 0.f ? 0x3F80u : (v.x < 0.f ? 0xBF80u : 0u);
    sg.y = v.y > 0.f ? 0x3F80u : (v.y < 0.f ? 0xBF80u : 0u);
    sg.z = v.z > 0.f ? 0x3F80u : (v.z < 0.f ? 0xBF80u : 0u);
    sg.w = v.w > 0.f ? 0x3F80u : (v.w < 0.f ? 0xBF80u : 0u);
    *reinterpret_cast<ushort4*>(orow + base) = sg;
  }
  for (int off = 32; off > 0; off >>= 1) s += __shfl_down(s, off);
  __shared__ float red[4];
  int lane = tid & 63, wid = tid >> 6;
  if (lane == 0) red[wid] = s;
  __syncthreads();
  if (tid == 0) alpha[o] = (red[0] + red[1] + red[2] + red[3]) / (float)K;
}

__global__ __launch_bounds__(256) void k_conv_x(const float* __restrict__ x,
                                                unsigned short* __restrict__ xb,
                                                long long n4) {
  long long i = (long long)blockIdx.x * blockDim.x + threadIdx.x;
  const long long stride = (long long)gridDim.x * blockDim.x;
  for (; i < n4; i += stride) {
    float4 v = reinterpret_cast<const float4*>(x)[i];
    ushort4 o;
    o.x = f2bf_rne(v.x);
    o.y = f2bf_rne(v.y);
    o.z = f2bf_rne(v.z);
    o.w = f2bf_rne(v.w);
    reinterpret_cast<ushort4*>(xb)[i] = o;
  }
}

// ---------- fallback: slow but correct, zero scratch
__global__ void k_naive(const float* __restrict__ x, const float* __restrict__ W,
                        const float* __restrict__ bias, float* __restrict__ out,
                        int M, int N, int K) {
  int m = blockIdx.x;
  int n = blockIdx.y * 256 + threadIdx.x;
  if (n >= N) return;
  const float* xr = x + (size_t)m * K;
  const float* wr = W + (size_t)n * K;
  float sa = 0.f, s = 0.f;
  for (int i = 0; i < K; ++i) {
    float wv = wr[i];
    sa += fabsf(wv);
    float sg = (wv > 0.f) ? 1.f : ((wv < 0.f) ? -1.f : 0.f);
    s += xr[i] * sg;
  }
  out[(size_t)m * N + n] = (sa / (float)K) * s + bias[n];
}

extern "C" void kernel_launch(void* const* d_in, const int* in_sizes, int n_in,
                              void* d_out, int out_size, void* d_ws, size_t ws_size,
                              hipStream_t stream) {
  const float* x = (const float*)d_in[0];
  const float* w = (const float*)d_in[1];
  const float* bias = (const float*)d_in[2];
  float* out = (float*)d_out;

  const int D_OUT = in_sizes[2];
  const int D_IN = in_sizes[1] / D_OUT;
  const long long M = (long long)in_sizes[0] / D_IN;
  const int N = D_OUT, K = D_IN;

  // i8 workspace layout: xq[M*K] | wq[N*K] | alpha[N] | srow[M]
  const size_t xqB = (size_t)M * K;
  const size_t wqB = (size_t)N * K;
  const size_t need_i8 = xqB + wqB + (size_t)N * 4 + (size_t)M * 4;
  // bf16 fallback layout: xb[M*K*2] | wb[N*K*2] | alpha[N]
  const size_t xbB = (size_t)M * K * 2;
  const size_t wbB = (size_t)N * K * 2;
  const size_t need_bf = xbB + wbB + (size_t)N * 4;

  const bool kok = (K % 1024 == 0);
  const bool f256i = kok && (ws_size >= need_i8) && (M % 128 == 0) && (N % 256 == 0) &&
                     (K % 128 == 0);
  const bool f128 = kok && (ws_size >= need_bf) && (M % 128 == 0) && (N % 128 == 0) &&
                    (K % 32 == 0);

  if (f256i) {
    signed char* xq = (signed char*)d_ws;
    signed char* wq = (signed char*)d_ws + xqB;
    float* alpha = (float*)((char*)d_ws + xqB + wqB);
    float* srow = alpha + N;
    k_prep_w_i8<<<N, 256, 0, stream>>>(w, wq, alpha, K);
    k_quant_x<<<(unsigned)M, 256, 0, stream>>>(x, xq, srow, K);
    const int tm = (int)(M / 128), tn = N / 256;
    k_gemm_i8<<<tm * tn, 512, 0, stream>>>(xq, wq, alpha, bias, srow, out,
                                           (int)M, N, K, tm, tn);
  } else if (f128) {
    unsigned short* xb = (unsigned short*)d_ws;
    unsigned short* wb = (unsigned short*)((char*)d_ws + xbB);
    float* alpha = (float*)((char*)d_ws + xbB + wbB);
    k_prep_w<<<N, 256, 0, stream>>>(w, wb, alpha, K);
    long long n4 = M * (long long)K / 4;
    k_conv_x<<<2048, 256, 0, stream>>>(x, xb, n4);
    const int tm = (int)(M / 128), tn = N / 128;
    k_gemm<<<tm * tn, 256, 0, stream>>>(xb, wb, alpha, bias, out, (int)M, N, K, tm);
  } else {
    dim3 g((unsigned)M, (unsigned)((N + 255) / 256));
    k_naive<<<g, 256, 0, stream>>>(x, w, bias, out, (int)M, N, K);
  }
}